// Round 1
// baseline (339.049 us; speedup 1.0000x reference)
//
#include <hip/hip_runtime.h>
#include <hip/hip_bf16.h>

typedef __bf16 bf16_t;
typedef bf16_t bf16x8 __attribute__((ext_vector_type(8)));
typedef bf16_t bf16x4 __attribute__((ext_vector_type(4)));
typedef float f32x4 __attribute__((ext_vector_type(4)));

#define DEVFN __device__ __forceinline__

// Problem constants
// H=8 D=31 T=4 P=50 C=248 O=744 B=512, DT=124, SCALE=31^-0.5
constexpr float SCALE = 0.17960530202677491f;
constexpr int KPAD = 256;   // padded C for QKV GEMM

DEVFN f32x4 mfma16(bf16x8 a, bf16x8 b, f32x4 c) {
    return __builtin_amdgcn_mfma_f32_16x16x32_bf16(a, b, c, 0, 0, 0);
}

// ---------------------------------------------------------------------------
// prep: pack W (744x248 f32 -> [768][256] bf16, zero pad), rel (99x124 f32 ->
// [112][128] bf16, zero pad), zero K-pad cols of q/k bufs and p-pad cols of vT.
// ---------------------------------------------------------------------------
__global__ void prep_kernel(const float* __restrict__ w, const float* __restrict__ rel,
                            bf16_t* __restrict__ Wp, bf16_t* __restrict__ relp,
                            bf16_t* __restrict__ qb, bf16_t* __restrict__ kb,
                            bf16_t* __restrict__ vb)
{
    long idx = (long)blockIdx.x * blockDim.x + threadIdx.x;
    if (idx < 196608) {                       // Wp: 768*256
        int o = (int)(idx >> 8), c = (int)(idx & 255);
        Wp[idx] = (o < 744 && c < 248) ? (bf16_t)w[o * 248 + c] : (bf16_t)0.f;
        return;
    }
    idx -= 196608;
    if (idx < 14336) {                        // relp: 112*128
        int r = (int)(idx >> 7), c = (int)(idx & 127);
        relp[idx] = (r < 99 && c < 124) ? (bf16_t)rel[r * 124 + c] : (bf16_t)0.f;
        return;
    }
    idx -= 14336;
    if (idx < 2097152) {                      // q/k pad cols 124..127, 262144 rows x 2 bufs
        long row = idx >> 3; int sub = (int)(idx & 7);
        bf16_t* buf = (sub & 4) ? kb : qb;
        buf[row * 128 + 124 + (sub & 3)] = (bf16_t)0.f;
        return;
    }
    idx -= 2097152;
    if (idx < 7340032) {                      // vT pad cols p=50..63, 524288 rows x 14
        long row = idx / 14;
        int cp = 50 + (int)(idx - row * 14);
        vb[row * 64 + cp] = (bf16_t)0.f;
    }
}

// ---------------------------------------------------------------------------
// QKV GEMM: qkv[o][col] = sum_c W[o][c] * x[b(col)][c][n(col)] + bias[o]
// Flat columns Cg = b*200 + n (n = p*4+t), 1600 blocks x 64 cols, M = 768 (all o).
// A = X^T staged in LDS (triple buffer, [col][k] bf16), B = Wp direct from global.
// C-frag: lane col (l&15) = o, rows (l>>4)*4+j = flat col -> j == t.
// Outputs: qb/kb as [b*8+h][p(64)][i(128)] bf16, vb as [b*8+h][i(128)][p(64)] bf16.
// ---------------------------------------------------------------------------
__global__ __launch_bounds__(512)
void qkv_kernel(const float* __restrict__ x, const float* __restrict__ bqkv,
                const bf16_t* __restrict__ Wp, bf16_t* __restrict__ qb,
                bf16_t* __restrict__ kb, bf16_t* __restrict__ vb)
{
    __shared__ __align__(16) bf16_t Xs[3][64][40];
    const int tid  = threadIdx.x;
    const int lane = tid & 63;
    const int wav  = tid >> 6;            // 0..7
    const int r15  = lane & 15;
    const int g4   = lane >> 4;           // 0..3
    const int cblk = blockIdx.x;          // 0..1599
    const int Cg0  = cblk * 64;

    // staging: thread -> (k-offset sc, 4 consecutive cols scol)
    const int sc   = tid >> 4;            // 0..31
    const int scol = (tid & 15) * 4;      // 0..60
    const int sb   = (Cg0 + scol) / 200;
    const int sn   = (Cg0 + scol) - sb * 200;
    const float* xs = x + (long)sb * 49600 + sn;

    auto stage = [&](int ks) {
        int c = ks * 32 + sc;
        float4 v;
        if (c < 248) v = *(const float4*)(xs + (long)c * 200);
        else         v = make_float4(0.f, 0.f, 0.f, 0.f);
        int bufi = ks % 3;
        Xs[bufi][scol + 0][sc] = (bf16_t)v.x;
        Xs[bufi][scol + 1][sc] = (bf16_t)v.y;
        Xs[bufi][scol + 2][sc] = (bf16_t)v.z;
        Xs[bufi][scol + 3][sc] = (bf16_t)v.w;
    };

    f32x4 acc[4][6];
#pragma unroll
    for (int m = 0; m < 4; ++m)
#pragma unroll
        for (int n = 0; n < 6; ++n) acc[m][n] = f32x4{0.f, 0.f, 0.f, 0.f};

    const int obase = wav * 96;
    const bf16_t* wp = Wp + (long)(obase + r15) * KPAD + g4 * 8;

    stage(0); stage(1);
    __syncthreads();

    bf16x8 Bf[6];
#pragma unroll
    for (int nt = 0; nt < 6; ++nt) Bf[nt] = *(const bf16x8*)(wp + nt * 16 * KPAD);

    for (int ks = 0; ks < 8; ++ks) {
        if (ks + 2 < 8) stage(ks + 2);
        bf16x8 Bn[6];
        if (ks + 1 < 8) {
#pragma unroll
            for (int nt = 0; nt < 6; ++nt)
                Bn[nt] = *(const bf16x8*)(wp + nt * 16 * KPAD + (ks + 1) * 32);
        }
        bf16x8 Af[4];
        const int bufi = ks % 3;
#pragma unroll
        for (int mt = 0; mt < 4; ++mt)
            Af[mt] = *(const bf16x8*)(&Xs[bufi][mt * 16 + r15][g4 * 8]);
#pragma unroll
        for (int mt = 0; mt < 4; ++mt)
#pragma unroll
            for (int nt = 0; nt < 6; ++nt)
                acc[mt][nt] = mfma16(Af[mt], Bf[nt], acc[mt][nt]);
        if (ks + 1 < 8) {
#pragma unroll
            for (int nt = 0; nt < 6; ++nt) Bf[nt] = Bn[nt];
        }
        __syncthreads();
    }

    // epilogue: scatter to q/k ([bh][p][i], packed 8B) and vT ([bh][i][p])
#pragma unroll
    for (int nt = 0; nt < 6; ++nt) {
        int o = obase + nt * 16 + r15;
        if (o >= 744) continue;
        int s   = o / 248;
        int rem = o - s * 248;
        int hh  = rem / 31;
        int dd  = rem - hh * 31;
        float bias = bqkv[o];
#pragma unroll
        for (int mt = 0; mt < 4; ++mt) {
            int Cg = Cg0 + mt * 16 + g4 * 4;
            int bb = Cg / 200;
            int nn = Cg - bb * 200;
            int pp = nn >> 2;             // t == j
            long bh = (long)bb * 8 + hh;
            f32x4 a = acc[mt][nt];
            if (s < 2) {
                bf16x4 pk;
                pk[0] = (bf16_t)(a[0] + bias);
                pk[1] = (bf16_t)(a[1] + bias);
                pk[2] = (bf16_t)(a[2] + bias);
                pk[3] = (bf16_t)(a[3] + bias);
                bf16_t* dst = (s == 0 ? qb : kb) + (bh * 64 + pp) * 128 + dd * 4;
                *(bf16x4*)dst = pk;
            } else {
#pragma unroll
                for (int j = 0; j < 4; ++j)
                    vb[(bh * 128 + dd * 4 + j) * 64 + pp] = (bf16_t)(a[j] + bias);
            }
        }
    }
}

// ---------------------------------------------------------------------------
// Attention: 1 block per (b,h); 4 waves, wave w owns q-rows w*16..w*16+15.
// Scores GEMM fused dots+bias: B cols 0..49 = k rows, 50..159 = rel rows.
// rel_to_abs == logit[p][j] += biasraw[p][j-p+49]  (LDS scatter-add).
// ---------------------------------------------------------------------------
__global__ __launch_bounds__(256)
void attn_kernel(const bf16_t* __restrict__ qb, const bf16_t* __restrict__ kb,
                 const bf16_t* __restrict__ vb, const bf16_t* __restrict__ relp,
                 float* __restrict__ out)
{
    __shared__ float Ls[64][72];
    __shared__ __align__(16) bf16_t As[64][72];
    const int bid = blockIdx.x;
    const int bb = bid >> 3, hh = bid & 7;
    const int tid  = threadIdx.x;
    const int lane = tid & 63;
    const int w    = tid >> 6;            // M-tile
    const int r15  = lane & 15, g4 = lane >> 4;

    const bf16_t* qbase = qb + (long)bid * (64 * 128);
    const bf16_t* kbase = kb + (long)bid * (64 * 128);
    const bf16_t* vbase = vb + (long)bid * (128 * 64);

    // ---- scores GEMM: M=16 rows (this wave), N=160, K=128 ----
    f32x4 acc[10];
#pragma unroll
    for (int nt = 0; nt < 10; ++nt) acc[nt] = f32x4{0.f, 0.f, 0.f, 0.f};

    bf16x8 Afr[4];
#pragma unroll
    for (int ks = 0; ks < 4; ++ks)
        Afr[ks] = *(const bf16x8*)(qbase + (w * 16 + r15) * 128 + ks * 32 + g4 * 8);

#pragma unroll
    for (int nt = 0; nt < 10; ++nt) {
        int col = nt * 16 + r15;
        const bf16_t* src = (col < 50) ? (kbase + col * 128) : (relp + (col - 50) * 128);
#pragma unroll
        for (int ks = 0; ks < 4; ++ks) {
            bf16x8 Bf = *(const bf16x8*)(src + ks * 32 + g4 * 8);
            acc[nt] = mfma16(Afr[ks], Bf, acc[nt]);
        }
    }

    // ---- pass A: store dots (c<50) into Ls ----
#pragma unroll
    for (int nt = 0; nt < 4; ++nt) {
        int c = nt * 16 + r15;
        if (c < 50) {
#pragma unroll
            for (int j = 0; j < 4; ++j) Ls[w * 16 + g4 * 4 + j][c] = acc[nt][j];
        }
    }
    __syncthreads();
    // ---- pass B: scatter-add bias (c>=50): j = c + p - 99 ----
#pragma unroll
    for (int nt = 3; nt < 10; ++nt) {
        int c = nt * 16 + r15;
        if (c >= 50) {
#pragma unroll
            for (int j = 0; j < 4; ++j) {
                int row = w * 16 + g4 * 4 + j;
                int jj = c + row - 99;
                if (jj >= 0 && jj < 50) Ls[row][jj] += acc[nt][j];
            }
        }
    }
    __syncthreads();

    // ---- softmax: 4 lanes per row ----
    const int srow = w * 16 + (lane >> 2);
    const int quad = lane & 3;
    if (srow < 50) {
        float mx = -1e30f;
        for (int jj = quad; jj < 50; jj += 4) mx = fmaxf(mx, Ls[srow][jj]);
        mx = fmaxf(mx, __shfl_xor(mx, 1));
        mx = fmaxf(mx, __shfl_xor(mx, 2));
        float sum = 0.f;
        for (int jj = quad; jj < 50; jj += 4) {
            float e = __expf((Ls[srow][jj] - mx) * SCALE);
            Ls[srow][jj] = e;
            sum += e;
        }
        sum += __shfl_xor(sum, 1);
        sum += __shfl_xor(sum, 2);
        float rs = 1.f / sum;
        for (int jj = quad; jj < 50; jj += 4) As[srow][jj] = (bf16_t)(Ls[srow][jj] * rs);
        for (int jj = 50 + quad; jj < 64; jj += 4) As[srow][jj] = (bf16_t)0.f;
    }
    __syncthreads();

    // ---- PV: M=16 rows, N=128 (i), K=64 (q') ----
    f32x4 acc2[8];
#pragma unroll
    for (int nt = 0; nt < 8; ++nt) acc2[nt] = f32x4{0.f, 0.f, 0.f, 0.f};
#pragma unroll
    for (int ks = 0; ks < 2; ++ks) {
        bf16x8 Af = *(const bf16x8*)(&As[w * 16 + r15][ks * 32 + g4 * 8]);
#pragma unroll
        for (int nt = 0; nt < 8; ++nt) {
            bf16x8 Bf = *(const bf16x8*)(vbase + (nt * 16 + r15) * 64 + ks * 32 + g4 * 8);
            acc2[nt] = mfma16(Af, Bf, acc2[nt]);
        }
    }

    // ---- store out[b][h*31+d][p][t] ----
    const long obase2 = ((long)bb * 248 + hh * 31) * 200;
#pragma unroll
    for (int nt = 0; nt < 8; ++nt) {
        int i = nt * 16 + r15;
        if (i >= 124) continue;
        int dd = i >> 2, tt = i & 3;
#pragma unroll
        for (int j = 0; j < 4; ++j) {
            int pp = w * 16 + g4 * 4 + j;
            if (pp < 50) out[obase2 + (long)dd * 200 + pp * 4 + tt] = acc2[nt][j];
        }
    }
}

// ---------------------------------------------------------------------------
extern "C" void kernel_launch(void* const* d_in, const int* in_sizes, int n_in,
                              void* d_out, int out_size, void* d_ws, size_t ws_size,
                              hipStream_t stream)
{
    const float* x   = (const float*)d_in[0];
    const float* wq  = (const float*)d_in[1];
    const float* bq  = (const float*)d_in[2];
    const float* rel = (const float*)d_in[3];
    float* out = (float*)d_out;

    char* ws = (char*)d_ws;
    bf16_t* Wp   = (bf16_t*)ws;                    // 768*256*2      = 393216 B
    bf16_t* relp = (bf16_t*)(ws + 393216);         // 112*128*2     = 28672 B
    bf16_t* qb   = (bf16_t*)(ws + 421888);         // 512*8*64*128*2 = 64 MiB
    bf16_t* kb   = qb + 33554432L;
    bf16_t* vb   = kb + 33554432L;
    // total ws: 421888 + 3*67108864 = 201,748,480 B

    prep_kernel<<<dim3(37688), dim3(256), 0, stream>>>(wq, rel, Wp, relp, qb, kb, vb);
    qkv_kernel<<<dim3(1600), dim3(512), 0, stream>>>(x, bq, Wp, qb, kb, vb);
    attn_kernel<<<dim3(4096), dim3(256), 0, stream>>>(qb, kb, vb, relp, out);
}

// Round 2
// 230.963 us; speedup vs baseline: 1.4680x; 1.4680x over previous
//
#include <hip/hip_runtime.h>
#include <hip/hip_bf16.h>

typedef __bf16 bf16_t;
typedef bf16_t bf16x8 __attribute__((ext_vector_type(8)));
typedef bf16_t bf16x4 __attribute__((ext_vector_type(4)));
typedef float f32x4 __attribute__((ext_vector_type(4)));

// H=8 D=31 T=4 P=50 C=248 O=744 B=512, DT=124, SCALE=31^-0.5
constexpr float SCALE = 0.17960530202677491f;

// LDS byte offsets (total 157,984 <= 163,840)
#define XT_OFF   0           // xT[200][256] bf16, swizzled chunks   (102,400 B)
#define QH_OFF   102400      // qh[50][128] bf16, swizzled           (12,800 B)
#define KH_OFF   115200      // kh[50][128] bf16, swizzled           (12,800 B)
#define AS_OFF   115200      // As[64][64] bf16 (aliases kh)         (8,192 B)
#define VT_OFF   128000      // vT[128][64] bf16, swizzled           (16,384 B)
#define LS_OFF   144384      // Ls[50][68] f32                       (13,600 B)
#define SMEM_BYTES 157984

__device__ __forceinline__ f32x4 mfma16(bf16x8 a, bf16x8 b, f32x4 c) {
    return __builtin_amdgcn_mfma_f32_16x16x32_bf16(a, b, c, 0, 0, 0);
}

// ---------------------------------------------------------------------------
// prep: pack W into per-(head,mtile,kstep) fragment-contiguous blocks,
// rel into fragment-contiguous blocks, bias into bp[h][96].
// Wf frag: flat = (((h*6+m)*8+ks)*64 + lane)*8 + e
//   row = m*16 + (lane&15) -> s=m>>1, d=(m&1)*16+(lane&15); c = ks*32+(lane>>4)*8+e
// relf frag: flat = (((rt*4+ks))*64 + lane)*8 + e ; r = rt*16+(lane&15), dt = ks*32+(lane>>4)*8+e
// ---------------------------------------------------------------------------
__global__ void prep_kernel(const float* __restrict__ w, const float* __restrict__ b_qkv,
                            const float* __restrict__ rel,
                            bf16_t* __restrict__ Wf, bf16_t* __restrict__ relf,
                            float* __restrict__ bp)
{
    int i = blockIdx.x * 256 + threadIdx.x;
    if (i < 196608) {                    // Wf
        int e = i & 7, lane = (i >> 3) & 63;
        int f = i >> 9;                  // (h*6+m)*8+ks
        int ks = f & 7, g = f >> 3;
        int h = g / 6, m = g - h * 6;
        int r15 = lane & 15, g4 = lane >> 4;
        int s = m >> 1, d = ((m & 1) << 4) + r15;
        int c = ks * 32 + g4 * 8 + e;
        float v = 0.f;
        if (d < 31 && c < 248) v = w[(long)(s * 248 + h * 31 + d) * 248 + c];
        Wf[i] = (bf16_t)v;
        return;
    }
    i -= 196608;
    if (i < 14336) {                     // relf
        int e = i & 7, lane = (i >> 3) & 63;
        int f = i >> 9;                  // rt*4+ks
        int ks = f & 3, rt = f >> 2;
        int r = rt * 16 + (lane & 15);
        int dt = ks * 32 + (lane >> 4) * 8 + e;
        float v = 0.f;
        if (r < 99 && dt < 124) v = rel[r * 124 + dt];
        relf[i] = (bf16_t)v;
        return;
    }
    i -= 14336;
    if (i < 768) {                       // bp[h][96]
        int h = i / 96, row = i - h * 96;
        int s = row >> 5, d = row & 31;
        bp[i] = (d < 31) ? b_qkv[s * 248 + h * 31 + d] : 0.f;
    }
}

// ---------------------------------------------------------------------------
// Fused kernel: one block per batch b. 512 threads = 8 waves.
// ---------------------------------------------------------------------------
__global__ __launch_bounds__(512, 2)
void fused_kernel(const float* __restrict__ x, const bf16_t* __restrict__ Wf,
                  const bf16_t* __restrict__ relf, const float* __restrict__ bp,
                  float* __restrict__ out)
{
    extern __shared__ char smem[];
    const int b    = blockIdx.x;
    const int tid  = threadIdx.x;
    const int lane = tid & 63;
    const int w    = tid >> 6;           // 0..7
    const int r15  = lane & 15, g4 = lane >> 4;

    // ================= phase 0: stage xT + zero pads =================
    {
        // zero vT entirely (pad cols 50..63 and rows 124..127 must stay 0)
        *(f32x4*)(smem + VT_OFF + tid * 32)      = f32x4{0.f, 0.f, 0.f, 0.f};
        *(f32x4*)(smem + VT_OFF + tid * 32 + 16) = f32x4{0.f, 0.f, 0.f, 0.f};
        // zero qh/kh dt-pad (cols 124..127), once per block (persists across heads)
        if (tid < 100) {
            int p = tid >> 1;
            int base = (tid & 1) ? KH_OFF : QH_OFF;
            int chunk = 15 ^ (p & 7);
            *(long*)(smem + base + p * 256 + chunk * 16 + 8) = 0L;
        }
        // zero xT c-pad (c=248..255) for real rows n<200
        if (tid < 200) {
            int chunk = 31 ^ ((tid >> 2) & 7);
            *(f32x4*)(smem + XT_OFF + tid * 512 + chunk * 16) = f32x4{0.f, 0.f, 0.f, 0.f};
        }
        // transpose-stage x[b]: wave w handles c rows w*31..w*31+30
        const float* xb = x + (long)b * 49600;
        const int q = lane;              // n-quad, active < 50
#pragma unroll 2
        for (int r = 0; r < 31; ++r) {
            int c = w * 31 + r;
            if (q < 50) {
                float4 v = *(const float4*)(xb + c * 200 + q * 4);
                int base = XT_OFF + (4 * q) * 512 + (((c >> 3) ^ (q & 7)) << 4) + (c & 7) * 2;
                *(bf16_t*)(smem + base)        = (bf16_t)v.x;   // n = 4q+0
                *(bf16_t*)(smem + base + 512)  = (bf16_t)v.y;   // n = 4q+1
                *(bf16_t*)(smem + base + 1024) = (bf16_t)v.z;
                *(bf16_t*)(smem + base + 1536) = (bf16_t)v.w;
            }
        }
    }
    __syncthreads();

    // ================= phase 1: load A fragments into registers =================
    // wave w: mu = w>>2 (m-trio), nu = w&3 (nt-quad, nt = 4*nu+ui, 16 nt total pad)
    const int mu = w >> 2;
    const int nu = w & 3;
    bf16x8 Areg[4][8];
#pragma unroll
    for (int ui = 0; ui < 4; ++ui) {
        int n = (nu * 4 + ui) * 16 + r15;          // up to 255 (overreads are discarded later)
        int hash = (n >> 2) & 7;
#pragma unroll
        for (int ks = 0; ks < 8; ++ks)
            Areg[ui][ks] = *(const bf16x8*)(smem + XT_OFF + n * 512 + ((((ks << 2) | g4) ^ hash) << 4));
    }
    __syncthreads();

    const int ptile = w >> 1, chalf = w & 1;

    // ================= head loop =================
    for (int h = 0; h < 8; ++h) {
        // ---- qkv GEMM: C[n][o] over c; A from regs, B from global frag-packed ----
#pragma unroll
        for (int m3 = 0; m3 < 3; ++m3) {
            int m = mu * 3 + m3;
            int s = m >> 1;
            int d = ((m & 1) << 4) + r15;          // 0..31
            float bias = bp[h * 96 + m * 16 + r15];
            f32x4 acc[4];
#pragma unroll
            for (int ui = 0; ui < 4; ++ui) acc[ui] = f32x4{0.f, 0.f, 0.f, 0.f};
            const bf16_t* wfrag = Wf + ((long)((h * 6 + m) * 8) << 9) + lane * 8;
#pragma unroll
            for (int ks = 0; ks < 8; ++ks) {
                bf16x8 Bf = *(const bf16x8*)(wfrag + (ks << 9));
#pragma unroll
                for (int ui = 0; ui < 4; ++ui)
                    acc[ui] = mfma16(Areg[ui][ks], Bf, acc[ui]);
            }
            if (d < 31) {
#pragma unroll
                for (int ui = 0; ui < 4; ++ui) {
                    int p = (nu * 4 + ui) * 4 + g4;
                    if (p >= 50) continue;
                    float a0 = acc[ui][0] + bias, a1 = acc[ui][1] + bias;
                    float a2 = acc[ui][2] + bias, a3 = acc[ui][3] + bias;
                    if (s < 2) {
                        bf16x4 pk = {(bf16_t)a0, (bf16_t)a1, (bf16_t)a2, (bf16_t)a3};
                        int base = (s == 0) ? QH_OFF : KH_OFF;
                        int chunk = (d >> 1) ^ (p & 7);
                        *(bf16x4*)(smem + base + p * 256 + chunk * 16 + ((d & 1) << 3)) = pk;
                    } else {
                        int chunk = ((p >> 3) ^ (d & 7)) << 4;
                        int vbase = VT_OFF + (d * 4) * 128 + chunk + (p & 7) * 2;
                        *(bf16_t*)(smem + vbase)       = (bf16_t)a0;   // row d*4+0
                        *(bf16_t*)(smem + vbase + 128) = (bf16_t)a1;
                        *(bf16_t*)(smem + vbase + 256) = (bf16_t)a2;
                        *(bf16_t*)(smem + vbase + 384) = (bf16_t)a3;
                    }
                }
            }
        }
        __syncthreads();

        // ---- scores: fused dots (cols 0..63 from kh) + rel bias (cols 64..175 global) ----
        bf16x8 Afr[4];
        {
            int p = ptile * 16 + r15;
            int hp = p & 7;
#pragma unroll
            for (int ks = 0; ks < 4; ++ks)
                Afr[ks] = *(const bf16x8*)(smem + QH_OFF + p * 256 + ((((ks << 2) | g4) ^ hp) << 4));
        }
        f32x4 sacc[6];
#pragma unroll
        for (int i = 0; i < 6; ++i) sacc[i] = f32x4{0.f, 0.f, 0.f, 0.f};
        const int nct = chalf ? 5 : 6;
        const int ct0 = chalf ? 6 : 0;
        for (int i = 0; i < nct; ++i) {
            int ct = ct0 + i;
            if (ct < 4) {
                int c = ct * 16 + r15;
                int hc = c & 7;
#pragma unroll
                for (int ks = 0; ks < 4; ++ks) {
                    bf16x8 Bf = *(const bf16x8*)(smem + KH_OFF + c * 256 + ((((ks << 2) | g4) ^ hc) << 4));
                    sacc[i] = mfma16(Afr[ks], Bf, sacc[i]);
                }
            } else {
                const bf16_t* rf = relf + (((ct - 4) * 4) << 9) + lane * 8;
#pragma unroll
                for (int ks = 0; ks < 4; ++ks) {
                    bf16x8 Bf = *(const bf16x8*)(rf + (ks << 9));
                    sacc[i] = mfma16(Afr[ks], Bf, sacc[i]);
                }
            }
        }
        // pass A: store dots
        if (chalf == 0) {
#pragma unroll
            for (int i = 0; i < 4; ++i) {
                int c = i * 16 + r15;
                if (c < 50) {
#pragma unroll
                    for (int j = 0; j < 4; ++j) {
                        int qrow = ptile * 16 + g4 * 4 + j;
                        if (qrow < 50)
                            *(float*)(smem + LS_OFF + (qrow * 68 + c) * 4) = sacc[i][j];
                    }
                }
            }
        }
        __syncthreads();
        // pass B: scatter-add rel bias: jj = r + qrow - 49
        for (int i = 0; i < nct; ++i) {
            int ct = ct0 + i;
            if (ct < 4) continue;
            int r = ct * 16 + r15 - 64;
#pragma unroll
            for (int j = 0; j < 4; ++j) {
                int qrow = ptile * 16 + g4 * 4 + j;
                int jj = r + qrow - 49;
                if (qrow < 50 && jj >= 0 && jj < 50) {
                    float* pL = (float*)(smem + LS_OFF + (qrow * 68 + jj) * 4);
                    *pL += sacc[i][j];
                }
            }
        }
        __syncthreads();
        // ---- softmax (8 lanes per row), write As (aliases kh) ----
        {
            int row = tid >> 3, sub = tid & 7;
            if (row < 50) {
                float mx = -1e30f;
                for (int jj = sub; jj < 50; jj += 8)
                    mx = fmaxf(mx, *(const float*)(smem + LS_OFF + (row * 68 + jj) * 4));
                mx = fmaxf(mx, __shfl_xor(mx, 1));
                mx = fmaxf(mx, __shfl_xor(mx, 2));
                mx = fmaxf(mx, __shfl_xor(mx, 4));
                float sum = 0.f;
                for (int jj = sub; jj < 50; jj += 8) {
                    float* pL = (float*)(smem + LS_OFF + (row * 68 + jj) * 4);
                    float e = __expf((*pL - mx) * SCALE);
                    *pL = e;
                    sum += e;
                }
                sum += __shfl_xor(sum, 1);
                sum += __shfl_xor(sum, 2);
                sum += __shfl_xor(sum, 4);
                float rs = 1.f / sum;
                int hrow = row & 7;
                for (int jj = sub; jj < 64; jj += 8) {
                    float v = 0.f;
                    if (jj < 50)
                        v = *(const float*)(smem + LS_OFF + (row * 68 + jj) * 4) * rs;
                    *(bf16_t*)(smem + AS_OFF + row * 128 + (((jj >> 3) ^ hrow) << 4) + (jj & 7) * 2) = (bf16_t)v;
                }
            }
        }
        __syncthreads();
        // ---- PV: C[i][p] = sum_{p'} vT[i][p'] * As[p][p'] ; coalesced float4 out ----
        {
            bf16x8 Av[2];
            int irow = w * 16 + r15;
            int hv = (irow >> 2) & 7;
#pragma unroll
            for (int ks = 0; ks < 2; ++ks)
                Av[ks] = *(const bf16x8*)(smem + VT_OFF + irow * 128 + ((((ks << 2) | g4) ^ hv) << 4));
            int dd = w * 4 + g4;           // d of this lane's 4 output rows (t=0..3)
#pragma unroll
            for (int pt = 0; pt < 4; ++pt) {
                f32x4 po = f32x4{0.f, 0.f, 0.f, 0.f};
                int prow = pt * 16 + r15;
                int hp = prow & 7;
#pragma unroll
                for (int ks = 0; ks < 2; ++ks) {
                    bf16x8 Bs = *(const bf16x8*)(smem + AS_OFF + prow * 128 + ((((ks << 2) | g4) ^ hp) << 4));
                    po = mfma16(Av[ks], Bs, po);
                }
                if (dd < 31 && prow < 50) {
                    *(f32x4*)(out + ((long)b * 248 + h * 31 + dd) * 200 + prow * 4) = po;
                }
            }
        }
        __syncthreads();   // protect qh/kh/As/vT rewrite by next head
    }
}

// ---------------------------------------------------------------------------
extern "C" void kernel_launch(void* const* d_in, const int* in_sizes, int n_in,
                              void* d_out, int out_size, void* d_ws, size_t ws_size,
                              hipStream_t stream)
{
    const float* x   = (const float*)d_in[0];
    const float* wq  = (const float*)d_in[1];
    const float* bq  = (const float*)d_in[2];
    const float* rel = (const float*)d_in[3];
    float* out = (float*)d_out;

    char* ws = (char*)d_ws;
    bf16_t* Wf   = (bf16_t*)ws;                    // 196,608 elems = 393,216 B
    bf16_t* relf = (bf16_t*)(ws + 393216);         // 14,336 elems  = 28,672 B
    float*  bp   = (float*)(ws + 421888);          // 768 f32       = 3,072 B

    const int B = in_sizes[0] / 49600;

    static int smem_set = -1;
    (void)smem_set;
    hipFuncSetAttribute((const void*)fused_kernel,
                        hipFuncAttributeMaxDynamicSharedMemorySize, SMEM_BYTES);

    prep_kernel<<<dim3(828), dim3(256), 0, stream>>>(wq, bq, rel, Wf, relf, bp);
    fused_kernel<<<dim3(B), dim3(512), SMEM_BYTES, stream>>>(x, Wf, relf, bp, out);
}